// Round 2
// baseline (405.723 us; speedup 1.0000x reference)
//
#include <hip/hip_runtime.h>
#include <hip/hip_bf16.h>
#include <cstdint>
#include <cstddef>

// TripletLoss: inputs (8192,128) fp32, targets (8192,) int32, 64 classes.
// out[0] = loss, out[1..] = dist (8192x8192) row-major fp32.
// v3: symmetry — only 2080 upper-triangle 128x128 tiles are computed (half
// the MFMA/convert work); each tile is stored twice (N + transposed T pass)
// via a 32KB LDS half-tile, both orientations row-contiguous. Hard-pos/neg
// reduction runs COLUMN-wise (valid by symmetry of d and the mask): each
// thread owns 4 fixed columns -> register accumulate across row-visits,
// zero per-iteration shuffles (was 160 DS-instr/wave). A/B fragments load
// directly from global (Xb 2MB, L2-resident) -> no staging barriers, LDS
// down to 32KB -> 3 blocks/CU.

#define NROWS 8192
#define DIMK  128
#define MARGIN 0.3f

typedef __bf16 bf16x8 __attribute__((ext_vector_type(8)));
typedef float  f32x4  __attribute__((ext_vector_type(4)));
typedef float  f32x2  __attribute__((ext_vector_type(2)));
typedef int    i32x4  __attribute__((ext_vector_type(4)));

__device__ __forceinline__ unsigned short f2bf(float f) {
    unsigned u = __float_as_uint(f);
    u += 0x7fffu + ((u >> 16) & 1u);
    return (unsigned short)(u >> 16);
}

// prep: bf16-convert X into linear Xb, row sq-norms from rounded values,
// init ap/an. grid 2048 x 256 (one wave per row).
__global__ __launch_bounds__(256) void prep_kernel(
    const float* __restrict__ X, unsigned short* __restrict__ Xb,
    float* __restrict__ sq, int* __restrict__ ap, int* __restrict__ an)
{
    const int t = blockIdx.x * 256 + threadIdx.x;
    if (t < NROWS) { ap[t] = 0; an[t] = 0x7f800000; }  // 0.0f / +inf
    const int row  = t >> 6;
    const int lane = t & 63;
    const f32x2 v = *(const f32x2*)(X + (size_t)row * DIMK + lane * 2);
    const unsigned short b0 = f2bf(v[0]);
    const unsigned short b1 = f2bf(v[1]);
    *(unsigned*)(Xb + (size_t)row * DIMK + lane * 2) =
        (unsigned)b0 | ((unsigned)b1 << 16);
    const float f0 = __uint_as_float((unsigned)b0 << 16);
    const float f1 = __uint_as_float((unsigned)b1 << 16);
    float s = f0 * f0 + f1 * f1;
    #pragma unroll
    for (int off = 32; off; off >>= 1) s += __shfl_xor(s, off);
    if (lane == 0) sq[row] = s;
}

// shifted row store: dist base is out+1, so write [4rc-1, 4rc+3) per lane
// (16B aligned) with the missing element pulled from the left neighbor.
__device__ __forceinline__ void store_row_shifted(float* drow, f32x4 d4, int rc) {
    const float prev = __shfl_up(d4[3], 1);
    if (rc == 0) {
        __builtin_nontemporal_store(d4[0], drow);
        const f32x2 v01 = {d4[1], d4[2]};
        __builtin_nontemporal_store(v01, (f32x2*)(drow + 1));
    } else {
        const f32x4 v = {prev, d4[0], d4[1], d4[2]};
        __builtin_nontemporal_store(v, (f32x4*)(drow + (rc << 2) - 1));
    }
    if (rc == 31)
        __builtin_nontemporal_store(d4[3], drow + 127);
}

__global__ __launch_bounds__(256, 3) void dist_kernel(
    const unsigned short* __restrict__ Xb, const float* __restrict__ sq,
    const int* __restrict__ tgt, float* __restrict__ dist,
    int* __restrict__ ap, int* __restrict__ an)
{
    __shared__ __align__(16) char lds[32 * 1024];  // C half-tile f32 64x128

    // ---- upper-triangle block decode: tri(m) = m*(129-m)/2 ----
    const int bid = blockIdx.x;
    int bm = (int)(0.5f * (129.0f - sqrtf(129.0f * 129.0f - 8.0f * (float)bid)));
    while ((bm + 1) * (129 - (bm + 1)) / 2 <= bid) bm++;
    while (bm * (129 - bm) / 2 > bid) bm--;
    const int bn = bm + (bid - bm * (129 - bm) / 2);   // bm <= bn

    const int t = threadIdx.x;
    const int lane = t & 63, wave = t >> 6;
    const int wm = (wave >> 1) << 6;   // 0 or 64
    const int wn = (wave & 1) << 6;
    const int l15 = lane & 15, quad = lane >> 4;
    const int rbase = bm << 7, cbase = bn << 7;
    const float INF = __int_as_float(0x7f800000);

    // ---- MFMA: fragments direct from global (L2-resident, no barriers) ----
    f32x4 acc[4][4];
    #pragma unroll
    for (int mi = 0; mi < 4; mi++)
        #pragma unroll
        for (int ni = 0; ni < 4; ni++)
            acc[mi][ni] = (f32x4){0.f, 0.f, 0.f, 0.f};

    const unsigned short* Arow = Xb + (size_t)(rbase + wm + l15) * DIMK;
    const unsigned short* Brow = Xb + (size_t)(cbase + wn + l15) * DIMK;
    #pragma unroll
    for (int ks = 0; ks < 4; ks++) {
        const int kb = ks * 32 + quad * 8;
        bf16x8 af[4], bfr[4];
        #pragma unroll
        for (int mi = 0; mi < 4; mi++)
            af[mi] = *(const bf16x8*)(Arow + mi * 16 * DIMK + kb);
        #pragma unroll
        for (int ni = 0; ni < 4; ni++)
            bfr[ni] = *(const bf16x8*)(Brow + ni * 16 * DIMK + kb);
        #pragma unroll
        for (int mi = 0; mi < 4; mi++)
            #pragma unroll
            for (int ni = 0; ni < 4; ni++)
                acc[mi][ni] = __builtin_amdgcn_mfma_f32_16x16x32_bf16(
                    af[mi], bfr[ni], acc[mi][ni], 0, 0, 0);
    }

    // ---- convert acc -> d in place (done once, reused by both passes) ----
    // C/D layout: col = lane&15, row = quad*4 + reg (per frag).
    int lcv[4]; float sqc[4];
    #pragma unroll
    for (int ni = 0; ni < 4; ni++) {
        lcv[ni] = wn + ni * 16 + l15;          // local col 0..127
        sqc[ni] = sq[cbase + lcv[ni]];
    }
    const bool diag = (bm == bn);
    #pragma unroll
    for (int mi = 0; mi < 4; mi++) {
        const int rl0 = wm + mi * 16 + quad * 4;
        const f32x4 sqr = *(const f32x4*)(sq + rbase + rl0);
        #pragma unroll
        for (int reg = 0; reg < 4; reg++) {
            const int rl = rl0 + reg;          // local row 0..127
            #pragma unroll
            for (int ni = 0; ni < 4; ni++) {
                const float sqd = sqr[reg] + sqc[ni] - 2.0f * acc[mi][ni][reg];
                float d = sqd > 0.0f ? sqrtf(sqd) : 0.0f;
                if (diag && rl == lcv[ni]) d = 0.0f;   // exact diagonal
                acc[mi][ni][reg] = d;
            }
        }
    }

    const int rc   = t & 31;   // fixed 16B col-chunk owned by this thread
    const int rsel = t >> 5;

    // ================= pass N: tile (bm,bn), reduce -> rows cbase+* ========
    {
        float apv[4] = {-1.f, -1.f, -1.f, -1.f};
        float anv[4] = {INF, INF, INF, INF};
        const i32x4 tc = *(const i32x4*)(tgt + cbase + rc * 4);
        #pragma unroll
        for (int h = 0; h < 2; h++) {
            __syncthreads();
            if (wm == h * 64) {                 // waves owning rows of half h
                #pragma unroll
                for (int mi = 0; mi < 4; mi++) {
                    #pragma unroll
                    for (int reg = 0; reg < 4; reg++) {
                        const int r = mi * 16 + quad * 4 + reg;  // local 0..63
                        const int sw = ((r >> 2) & 1) << 6;      // 2-way banks
                        #pragma unroll
                        for (int ni = 0; ni < 4; ni++)
                            *(float*)(lds + r * 512 + ((lcv[ni] << 2) ^ sw)) =
                                acc[mi][ni][reg];
                    }
                }
            }
            __syncthreads();
            #pragma unroll
            for (int it = 0; it < 8; it++) {
                const int r = it * 8 + rsel;
                const f32x4 d4 = *(const f32x4*)(
                    lds + r * 512 + ((rc << 4) ^ ((((r >> 2) & 1)) << 6)));
                const int rowg = rbase + h * 64 + r;
                store_row_shifted(dist + (size_t)rowg * NROWS + cbase, d4, rc);
                const int trg = tgt[rowg];
                #pragma unroll
                for (int j = 0; j < 4; j++) {
                    const bool same = (trg == tc[j]);
                    apv[j] = fmaxf(apv[j], same ? d4[j] : -1.f);
                    anv[j] = fminf(anv[j], same ? INF : d4[j]);
                }
            }
        }
        #pragma unroll
        for (int j = 0; j < 4; j++) {
            apv[j] = fmaxf(apv[j], __shfl_xor(apv[j], 32));
            anv[j] = fminf(anv[j], __shfl_xor(anv[j], 32));
        }
        if (lane < 32) {
            #pragma unroll
            for (int j = 0; j < 4; j++) {
                atomicMax(ap + cbase + rc * 4 + j, __float_as_int(apv[j]));
                atomicMin(an + cbase + rc * 4 + j, __float_as_int(anv[j]));
            }
        }
    }

    // ============ pass T: tile (bn,bm), reduce -> rows rbase+* =============
    if (!diag) {
        float apv[4] = {-1.f, -1.f, -1.f, -1.f};
        float anv[4] = {INF, INF, INF, INF};
        const i32x4 tc = *(const i32x4*)(tgt + rbase + rc * 4);
        #pragma unroll
        for (int h = 0; h < 2; h++) {
            __syncthreads();
            if (wn == h * 64) {                 // waves owning cols of half h
                #pragma unroll
                for (int ni = 0; ni < 4; ni++) {
                    const int cl = ni * 16 + l15;        // local T-row 0..63
                    #pragma unroll
                    for (int mi = 0; mi < 4; mi++) {
                        const int rl0 = wm + mi * 16 + quad * 4;  // T-col
                        // acc[mi][ni] = 4 consecutive rows = 4 consec T-cols
                        *(f32x4*)(lds + cl * 512 +
                                  ((rl0 << 2) ^ ((cl & 7) << 4))) = acc[mi][ni];
                    }
                }
            }
            __syncthreads();
            #pragma unroll
            for (int it = 0; it < 8; it++) {
                const int c = it * 8 + rsel;             // local T-row
                const f32x4 d4 = *(const f32x4*)(
                    lds + c * 512 + ((rc << 4) ^ ((c & 7) << 4)));
                const int rowg = cbase + h * 64 + c;
                store_row_shifted(dist + (size_t)rowg * NROWS + rbase, d4, rc);
                const int trg = tgt[rowg];
                #pragma unroll
                for (int j = 0; j < 4; j++) {
                    const bool same = (trg == tc[j]);
                    apv[j] = fmaxf(apv[j], same ? d4[j] : -1.f);
                    anv[j] = fminf(anv[j], same ? INF : d4[j]);
                }
            }
        }
        #pragma unroll
        for (int j = 0; j < 4; j++) {
            apv[j] = fmaxf(apv[j], __shfl_xor(apv[j], 32));
            anv[j] = fminf(anv[j], __shfl_xor(anv[j], 32));
        }
        if (lane < 32) {
            #pragma unroll
            for (int j = 0; j < 4; j++) {
                atomicMax(ap + rbase + rc * 4 + j, __float_as_int(apv[j]));
                atomicMin(an + rbase + rc * 4 + j, __float_as_int(anv[j]));
            }
        }
    }
}

__global__ __launch_bounds__(256) void loss_kernel(
    const int* __restrict__ ap, const int* __restrict__ an,
    float* __restrict__ out)
{
    __shared__ float red[4];
    float s = 0.0f;
    for (int i = threadIdx.x; i < NROWS; i += 256) {
        const float v = __int_as_float(ap[i]) - __int_as_float(an[i]) + MARGIN;
        s += v > 0.0f ? v : 0.0f;
    }
    #pragma unroll
    for (int off = 32; off; off >>= 1) s += __shfl_xor(s, off);
    if ((threadIdx.x & 63) == 0) red[threadIdx.x >> 6] = s;
    __syncthreads();
    if (threadIdx.x == 0)
        out[0] = (red[0] + red[1] + red[2] + red[3]) * (1.0f / NROWS);
}

extern "C" void kernel_launch(void* const* d_in, const int* in_sizes, int n_in,
                              void* d_out, int out_size, void* d_ws, size_t ws_size,
                              hipStream_t stream)
{
    const float* X   = (const float*)d_in[0];
    const int*   tgt = (const int*)d_in[1];
    float*       out = (float*)d_out;

    // ws layout: Xb bf16 8192x128 linear (2 MB) | sq (32 KB) | ap | an
    unsigned short* Xb = (unsigned short*)d_ws;
    float* sq = (float*)((char*)d_ws + (size_t)NROWS * DIMK * 2);
    int*   ap = (int*)(sq + NROWS);
    int*   an = ap + NROWS;

    prep_kernel<<<(NROWS * 64) / 256, 256, 0, stream>>>(X, Xb, sq, ap, an);

    dist_kernel<<<2080, 256, 0, stream>>>(Xb, sq, tgt, out + 1, ap, an);

    loss_kernel<<<1, 256, 0, stream>>>(ap, an, out);
}

// Round 3
// 332.519 us; speedup vs baseline: 1.2201x; 1.2201x over previous
//
#include <hip/hip_runtime.h>
#include <hip/hip_bf16.h>
#include <cstdint>
#include <cstddef>

// TripletLoss: inputs (8192,128) fp32, targets (8192,) int32, 64 classes.
// out[0] = loss, out[1..] = dist (8192x8192) row-major fp32.
// v4: back to v2 skeleton (full 64x64 grid, LDS-staged A/B with pre-swizzled
// Xb, conflict-free MFMA reads, C staged through LDS, row-contiguous aligned
// readback) with two changes driven by the v1-v3 counter evidence:
//  (1) ALL dist stores are REGULAR (L2-allocating), not nontemporal. NT
//      no-allocate left every tile-edge partial line unmergeable -> DRAM RMW,
//      1.1-1.5x write amplification, ~2 TB/s cap; the 6.3 TB/s fill kernel
//      proves plain full-line stores stream at full BW. Barriers now drain
//      stores at L2, not DRAM.
//  (2) zero-shuffle column-register reduce (from v3, valid on the full grid
//      by symmetry of d and the mask): each thread owns 4 fixed columns,
//      accumulates in registers across all 16 row-visits, then 1 shfl_xor +
//      LDS atomics + 256 global atomics/block. Replaces the 160-shfl/lane
//      epilogue that kept VALUBusy at 35-40% in v1/v2.

#define NROWS 8192
#define DIMK  128
#define MARGIN 0.3f

typedef __bf16 bf16x8 __attribute__((ext_vector_type(8)));
typedef float  f32x4  __attribute__((ext_vector_type(4)));
typedef float  f32x2  __attribute__((ext_vector_type(2)));
typedef int    i32x4  __attribute__((ext_vector_type(4)));

__device__ __forceinline__ unsigned short f2bf(float f) {
    // round-to-nearest-even fp32 -> bf16
    unsigned u = __float_as_uint(f);
    u += 0x7fffu + ((u >> 16) & 1u);
    return (unsigned short)(u >> 16);
}

// prep: bf16-convert X into Xb with a per-row 16B-chunk XOR swizzle
// (byte ^= (row&7)<<4 within the 256B row), row sq-norms from the ROUNDED
// values, init ap/an. grid 2048 x 256 (one wave per row).
__global__ __launch_bounds__(256) void prep_kernel(
    const float* __restrict__ X, unsigned short* __restrict__ Xb,
    float* __restrict__ sq, int* __restrict__ ap, int* __restrict__ an)
{
    const int t = blockIdx.x * 256 + threadIdx.x;
    if (t < NROWS) { ap[t] = 0; an[t] = 0x7f800000; }  // 0.0f / +inf
    const int row  = t >> 6;
    const int lane = t & 63;
    const f32x2 v = *(const f32x2*)(X + (size_t)row * DIMK + lane * 2);
    const unsigned short b0 = f2bf(v[0]);
    const unsigned short b1 = f2bf(v[1]);
    const int swz = (row & 7) << 4;
    *(unsigned*)((char*)Xb + (size_t)row * 256 + ((lane * 4) ^ swz)) =
        (unsigned)b0 | ((unsigned)b1 << 16);
    const float f0 = __uint_as_float((unsigned)b0 << 16);
    const float f1 = __uint_as_float((unsigned)b1 << 16);
    float s = f0 * f0 + f1 * f1;
    #pragma unroll
    for (int off = 32; off; off >>= 1) s += __shfl_xor(s, off);
    if (lane == 0) sq[row] = s;
}

// shifted row store: dist base is out+1, so per lane write [4rc-1, 4rc+3)
// (16B aligned) with the missing element pulled from the left neighbor.
// REGULAR stores: edge partial lines merge with neighbor blocks in L2.
__device__ __forceinline__ void store_row_shifted(float* drow, f32x4 d4, int rc) {
    const float prev = __shfl_up(d4[3], 1);
    if (rc == 0) {
        drow[0] = d4[0];
        *(f32x2*)(drow + 1) = (f32x2){d4[1], d4[2]};
    } else {
        *(f32x4*)(drow + (rc << 2) - 1) = (f32x4){prev, d4[0], d4[1], d4[2]};
    }
    if (rc == 31)
        drow[127] = d4[3];
}

__global__ __launch_bounds__(256, 2) void dist_kernel(
    const unsigned short* __restrict__ Xb, const float* __restrict__ sq,
    const int* __restrict__ tgt, float* __restrict__ dist,
    int* __restrict__ ap, int* __restrict__ an)
{
    __shared__ __align__(16) char lds[64 * 1024];  // A(32K)+B(32K) -> C(64K)
    __shared__ int apL[128], anL[128];

    const int t  = threadIdx.x;
    const int bm = blockIdx.x, bn = blockIdx.y;

    if (t < 128) { apL[t] = 0; anL[t] = 0x7f800000; }

    // ---- stage A and B tiles (each: 128 rows x 256B, contiguous) ----
    {
        const char* gA = (const char*)Xb + (size_t)bm * 32768;
        const char* gB = (const char*)Xb + (size_t)bn * 32768;
        #pragma unroll
        for (int i = 0; i < 8; i++) {
            const int off = i * 4096 + t * 16;
            __builtin_amdgcn_global_load_lds(
                (const __attribute__((address_space(1))) void*)(gA + off),
                (__attribute__((address_space(3))) void*)(lds + off),
                16, 0, 0);
            __builtin_amdgcn_global_load_lds(
                (const __attribute__((address_space(1))) void*)(gB + off),
                (__attribute__((address_space(3))) void*)(lds + 32768 + off),
                16, 0, 0);
        }
    }
    __syncthreads();

    const int lane = t & 63, wave = t >> 6;
    const int wm = (wave >> 1) << 6;   // 0 or 64
    const int wn = (wave & 1) << 6;
    const int l15 = lane & 15, quad = lane >> 4;
    const int rbase = bm << 7, cbase = bn << 7;
    const float INF = __int_as_float(0x7f800000);

    f32x4 acc[4][4];
    #pragma unroll
    for (int mi = 0; mi < 4; mi++)
        #pragma unroll
        for (int ni = 0; ni < 4; ni++)
            acc[mi][ni] = (f32x4){0.f, 0.f, 0.f, 0.f};

    // ---- MFMA K loop: 4 k-steps of 32, swizzled conflict-free LDS reads ----
    #pragma unroll
    for (int ks = 0; ks < 4; ks++) {
        const int kb2 = ks * 64 + quad * 16;  // byte offset of 16B k-chunk
        bf16x8 af[4], bfr[4];
        #pragma unroll
        for (int mi = 0; mi < 4; mi++) {
            const int r = wm + mi * 16 + l15;
            af[mi] = *(const bf16x8*)(lds + r * 256 + (kb2 ^ ((r & 7) << 4)));
        }
        #pragma unroll
        for (int ni = 0; ni < 4; ni++) {
            const int c = wn + ni * 16 + l15;
            bfr[ni] = *(const bf16x8*)(lds + 32768 + c * 256 + (kb2 ^ ((c & 7) << 4)));
        }
        #pragma unroll
        for (int mi = 0; mi < 4; mi++)
            #pragma unroll
            for (int ni = 0; ni < 4; ni++)
                acc[mi][ni] = __builtin_amdgcn_mfma_f32_16x16x32_bf16(
                    af[mi], bfr[ni], acc[mi][ni], 0, 0, 0);
    }

    __syncthreads();  // all frag reads retired before C-tile overwrites A/B

    // ---- convert sqd -> d and stage into LDS f32[128][128], 16B-chunk XOR --
    // C/D layout: col = lane&15, row = quad*4 + reg (per frag).
    int lcv[4]; float sqc[4];
    #pragma unroll
    for (int ni = 0; ni < 4; ni++) {
        lcv[ni] = wn + ni * 16 + l15;          // local col 0..127
        sqc[ni] = sq[cbase + lcv[ni]];
    }
    #pragma unroll
    for (int mi = 0; mi < 4; mi++) {
        const int rl0 = wm + mi * 16 + quad * 4;
        const f32x4 sqr = *(const f32x4*)(sq + rbase + rl0);
        #pragma unroll
        for (int reg = 0; reg < 4; reg++) {
            const int rl  = rl0 + reg;         // local row 0..127
            const int rg  = rbase + rl;
            const int swz = (rl & 7) << 4;
            #pragma unroll
            for (int ni = 0; ni < 4; ni++) {
                const float sqd = sqr[reg] + sqc[ni] - 2.0f * acc[mi][ni][reg];
                float d = sqd > 0.0f ? sqrtf(sqd) : 0.0f;
                if (rg == cbase + lcv[ni]) d = 0.0f;   // exact diagonal
                *(float*)(lds + rl * 512 + ((lcv[ni] << 2) ^ swz)) = d;
            }
        }
    }
    __syncthreads();

    // ---- readback: row-contiguous aligned stores + column-register reduce --
    // thread owns fixed col-chunk rc (cols 4rc..4rc+3); visits 16 rows.
    const int rc = t & 31;
    const int w  = t >> 5;
    float apv[4] = {-1.f, -1.f, -1.f, -1.f};
    float anv[4] = {INF, INF, INF, INF};
    const i32x4 tc = *(const i32x4*)(tgt + cbase + rc * 4);

    #pragma unroll 4
    for (int it = 0; it < 16; it++) {
        const int r = it * 8 + w;              // local row
        const f32x4 d4 = *(const f32x4*)(lds + r * 512 + ((rc ^ (r & 7)) << 4));
        const int rg = rbase + r;
        store_row_shifted(dist + (size_t)rg * NROWS + cbase, d4, rc);
        const int trg = tgt[rg];
        #pragma unroll
        for (int j = 0; j < 4; j++) {
            const bool same = (trg == tc[j]);
            apv[j] = fmaxf(apv[j], same ? d4[j] : -1.f);
            anv[j] = fminf(anv[j], same ? INF : d4[j]);
        }
    }
    // combine the two half-wave partials, then cross-wave via LDS atomics
    #pragma unroll
    for (int j = 0; j < 4; j++) {
        apv[j] = fmaxf(apv[j], __shfl_xor(apv[j], 32));
        anv[j] = fminf(anv[j], __shfl_xor(anv[j], 32));
    }
    if (lane < 32) {
        #pragma unroll
        for (int j = 0; j < 4; j++) {
            atomicMax(apL + rc * 4 + j, __float_as_int(apv[j]));
            atomicMin(anL + rc * 4 + j, __float_as_int(anv[j]));
        }
    }
    __syncthreads();
    if (t < 128) {
        atomicMax(ap + cbase + t, apL[t]);
        atomicMin(an + cbase + t, anL[t]);
    }
}

__global__ __launch_bounds__(256) void loss_kernel(
    const int* __restrict__ ap, const int* __restrict__ an,
    float* __restrict__ out)
{
    __shared__ float red[4];
    float s = 0.0f;
    for (int i = threadIdx.x; i < NROWS; i += 256) {
        const float v = __int_as_float(ap[i]) - __int_as_float(an[i]) + MARGIN;
        s += v > 0.0f ? v : 0.0f;
    }
    #pragma unroll
    for (int off = 32; off; off >>= 1) s += __shfl_xor(s, off);
    if ((threadIdx.x & 63) == 0) red[threadIdx.x >> 6] = s;
    __syncthreads();
    if (threadIdx.x == 0)
        out[0] = (red[0] + red[1] + red[2] + red[3]) * (1.0f / NROWS);
}

extern "C" void kernel_launch(void* const* d_in, const int* in_sizes, int n_in,
                              void* d_out, int out_size, void* d_ws, size_t ws_size,
                              hipStream_t stream)
{
    const float* X   = (const float*)d_in[0];
    const int*   tgt = (const int*)d_in[1];
    float*       out = (float*)d_out;

    // ws layout: Xb bf16 8192x128 swizzled (2 MB) | sq (32 KB) | ap | an
    unsigned short* Xb = (unsigned short*)d_ws;
    float* sq = (float*)((char*)d_ws + (size_t)NROWS * DIMK * 2);
    int*   ap = (int*)(sq + NROWS);
    int*   an = ap + NROWS;

    prep_kernel<<<(NROWS * 64) / 256, 256, 0, stream>>>(X, Xb, sq, ap, an);

    dim3 grid(64, 64);
    dist_kernel<<<grid, 256, 0, stream>>>(Xb, sq, tgt, out + 1, ap, an);

    loss_kernel<<<1, 256, 0, stream>>>(ap, an, out);
}